// Round 2
// baseline (106.193 us; speedup 1.0000x reference)
//
#include <hip/hip_runtime.h>

#define BB 16
#define NN 8
#define CC 3
#define HH 256
#define WW 256
#define PLANE (HH * WW)          // 65536
#define SLICE (CC * PLANE)       // 196608 elems per (b,n)

// 8192 blocks total = 16 b * 8 n * 64 blocks. XCD-affinity swizzle:
// blockIdx.x % 8 ~ XCD (dispatch round-robin). Image b is pinned to XCD b&7
// so its 768 KB stays resident in that XCD's 4 MB L2.
// Per thread: 4 consecutive x pixels, all 3 channels, float4 stores.
__global__ __launch_bounds__(256) void warp_kernel(
    const float* __restrict__ img,   // [B][C][H][W]
    const float* __restrict__ tf,    // [B][N][6]
    float* __restrict__ out,         // [B][N][C][H][W]
    int* __restrict__ flags)         // [B*N] nonzero-seen flags
{
    // --- XCD-affine decode ---
    int slot = blockIdx.x;
    int xcd  = slot & 7;             // target XCD
    int j    = slot >> 3;            // 0..1023 within XCD
    int b    = xcd + ((j >> 9) << 3);// images b = xcd and xcd+8 on this XCD
    int wi   = j & 511;              // 0..511: 8 n * 64 blocks
    int n    = wi >> 6;
    int blk  = wi & 63;
    int bn   = (b << 3) + n;

    int t = (blk << 8) + threadIdx.x;    // 0..16383 within (b,n)
    int x = (t & 63) << 2;
    int y = t >> 6;                      // 0..255

    const float* M = tf + bn * 6;
    float a  = M[0], bm = M[1], tx = M[2];
    float c  = M[3], d  = M[4], ty = M[5];
    float det = a * d - bm * c;
    float ia  =  d / det;
    float ib  = -bm / det;
    float ic  = -c / det;
    float idm =  a / det;

    const float* imgb = img + (size_t)b * SLICE;
    float dy = (float)y - ty;

    // ---- pass 1: addresses + mask-folded weights ----
    int   idx[4][4];     // [pixel][tap]  tap order: 00,01,10,11
    float w[4][4];
#pragma unroll
    for (int p = 0; p < 4; ++p) {
        float dx = (float)(x + p) - tx;
        float sx = ia * dx + ib * dy;
        float sy = ic * dx + idm * dy;
        float x0f = floorf(sx);
        float y0f = floorf(sy);
        float wx = sx - x0f;
        float wy = sy - y0f;
        int x0 = (int)x0f;
        int y0 = (int)y0f;

        float mx0 = (x0 >= 0 && x0 < WW)         ? 1.f : 0.f;
        float mx1 = (x0 + 1 >= 0 && x0 + 1 < WW) ? 1.f : 0.f;
        float my0 = (y0 >= 0 && y0 < HH)         ? 1.f : 0.f;
        float my1 = (y0 + 1 >= 0 && y0 + 1 < HH) ? 1.f : 0.f;

        int xc0 = min(max(x0, 0), WW - 1);
        int xc1 = min(max(x0 + 1, 0), WW - 1);
        int yc0 = min(max(y0, 0), HH - 1);
        int yc1 = min(max(y0 + 1, 0), HH - 1);

        idx[p][0] = yc0 * WW + xc0;
        idx[p][1] = yc0 * WW + xc1;
        idx[p][2] = yc1 * WW + xc0;
        idx[p][3] = yc1 * WW + xc1;

        w[p][0] = (1.f - wx) * (1.f - wy) * (mx0 * my0);
        w[p][1] = wx * (1.f - wy)         * (mx1 * my0);
        w[p][2] = (1.f - wx) * wy         * (mx0 * my1);
        w[p][3] = wx * wy                 * (mx1 * my1);
    }

    // ---- pass 2: issue all 48 gathers (maximize loads in flight) ----
    float v[4][CC][4];   // [pixel][channel][tap]
#pragma unroll
    for (int p = 0; p < 4; ++p) {
#pragma unroll
        for (int ch = 0; ch < CC; ++ch) {
            const float* pc = imgb + ch * PLANE;
            v[p][ch][0] = pc[idx[p][0]];
            v[p][ch][1] = pc[idx[p][1]];
            v[p][ch][2] = pc[idx[p][2]];
            v[p][ch][3] = pc[idx[p][3]];
        }
    }

    // ---- pass 3: combine + store ----
    bool nz = false;
    size_t base = (size_t)bn * SLICE + (size_t)y * WW + x;
#pragma unroll
    for (int ch = 0; ch < CC; ++ch) {
        float r[4];
#pragma unroll
        for (int p = 0; p < 4; ++p) {
            float o = v[p][ch][0] * w[p][0] + v[p][ch][1] * w[p][1]
                    + v[p][ch][2] * w[p][2] + v[p][ch][3] * w[p][3];
            r[p] = o;
            nz |= (o != 0.f);
        }
        *reinterpret_cast<float4*>(out + base + (size_t)ch * PLANE) =
            make_float4(r[0], r[1], r[2], r[3]);
    }

    // all-zero detection: one atomic per block
    __shared__ int s_nz;
    if (threadIdx.x == 0) s_nz = 0;
    __syncthreads();
    if (nz) s_nz = 1;            // benign race: all writers store 1
    __syncthreads();
    if (threadIdx.x == 0 && s_nz) atomicOr(&flags[bn], 1);
}

// If a (b,n) slice produced no nonzero element, overwrite it with -1.
__global__ __launch_bounds__(256) void fixup_kernel(
    float* __restrict__ out, const int* __restrict__ flags)
{
    int bn = blockIdx.x;
    if (flags[bn] != 0) return;
    float4 m1 = make_float4(-1.f, -1.f, -1.f, -1.f);
    float4* o4 = reinterpret_cast<float4*>(out + (size_t)bn * SLICE);
    for (int i = threadIdx.x; i < SLICE / 4; i += 256) o4[i] = m1;
}

extern "C" void kernel_launch(void* const* d_in, const int* in_sizes, int n_in,
                              void* d_out, int out_size, void* d_ws, size_t ws_size,
                              hipStream_t stream) {
    (void)in_sizes; (void)n_in; (void)out_size; (void)ws_size;
    const float* img = (const float*)d_in[0];
    const float* tf  = (const float*)d_in[1];
    float* out = (float*)d_out;
    int* flags = (int*)d_ws;

    hipMemsetAsync(flags, 0, BB * NN * sizeof(int), stream);

    int total_threads = BB * NN * HH * WW / 4;   // 2,097,152
    warp_kernel<<<total_threads / 256, 256, 0, stream>>>(img, tf, out, flags);
    fixup_kernel<<<BB * NN, 256, 0, stream>>>(out, flags);
}

// Round 3
// 65.031 us; speedup vs baseline: 1.6330x; 1.6330x over previous
//
#include <hip/hip_runtime.h>

#define BB 16
#define NN 8
#define CC 3
#define HH 256
#define WW 256
#define PLANE (HH * WW)          // 65536
#define SLICE (CC * PLANE)       // 196608 elems per (b,n)

// 8192 blocks = 16 b * 8 n * 64 row-groups. XCD-affinity swizzle: image b is
// pinned to XCD b&7 so its 768 KB stays resident in that XCD's 4 MB L2.
// Work mapping (gather-coalescing): thread owns ONE x (x = threadIdx.x, so
// gather lanes are unit-stride -> 2-3 cache lines per wave-load instead of
// ~32 at the old 16B lane stride) and FOUR consecutive y rows.
__global__ __launch_bounds__(256) void warp_kernel(
    const float* __restrict__ img,   // [B][C][H][W]
    const float* __restrict__ tf,    // [B][N][6]
    float* __restrict__ out,         // [B][N][C][H][W]
    int* __restrict__ flags)         // [B*N] nonzero-seen flags
{
    // --- XCD-affine decode ---
    int slot = blockIdx.x;
    int xcd  = slot & 7;              // target XCD
    int j    = slot >> 3;             // 0..1023 within XCD
    int b    = xcd + ((j >> 9) << 3); // images b = xcd and xcd+8 on this XCD
    int wi   = j & 511;               // 0..511: 8 n * 64 row-groups
    int n    = wi >> 6;
    int blk  = wi & 63;               // row-group: rows [blk*4, blk*4+4)
    int bn   = (b << 3) + n;

    int x  = threadIdx.x;             // 0..255, lane-consecutive
    int yb = blk << 2;

    const float* M = tf + bn * 6;
    float a  = M[0], bm = M[1], tx = M[2];
    float c  = M[3], d  = M[4], ty = M[5];
    float det = a * d - bm * c;
    float ia  =  d / det;
    float ib  = -bm / det;
    float ic  = -c / det;
    float idm =  a / det;

    const float* imgb = img + (size_t)b * SLICE;
    float dx = (float)x - tx;
    float sxb = ia * dx;              // row-invariant parts
    float syb = ic * dx;

    bool nz = false;
    float* orow = out + (size_t)bn * SLICE + (size_t)yb * WW + x;

#pragma unroll
    for (int p = 0; p < 4; ++p) {
        float dy = (float)(yb + p) - ty;
        float sx = sxb + ib * dy;
        float sy = syb + idm * dy;
        float x0f = floorf(sx);
        float y0f = floorf(sy);
        float wx = sx - x0f;
        float wy = sy - y0f;
        int x0 = (int)x0f;
        int y0 = (int)y0f;

        float mx0 = (x0 >= 0 && x0 < WW)         ? 1.f : 0.f;
        float mx1 = (x0 + 1 >= 0 && x0 + 1 < WW) ? 1.f : 0.f;
        float my0 = (y0 >= 0 && y0 < HH)         ? 1.f : 0.f;
        float my1 = (y0 + 1 >= 0 && y0 + 1 < HH) ? 1.f : 0.f;

        int xc0 = min(max(x0, 0), WW - 1);
        int xc1 = min(max(x0 + 1, 0), WW - 1);
        int yc0 = min(max(y0, 0), HH - 1);
        int yc1 = min(max(y0 + 1, 0), HH - 1);

        int i00 = yc0 * WW + xc0;
        int i01 = yc0 * WW + xc1;
        int i10 = yc1 * WW + xc0;
        int i11 = yc1 * WW + xc1;

        float w00 = (1.f - wx) * (1.f - wy) * (mx0 * my0);
        float w01 = wx * (1.f - wy)         * (mx1 * my0);
        float w10 = (1.f - wx) * wy         * (mx0 * my1);
        float w11 = wx * wy                 * (mx1 * my1);

        // 12 gathers in flight (unit-stride lanes -> coalesced)
        float v[CC][4];
#pragma unroll
        for (int ch = 0; ch < CC; ++ch) {
            const float* pc = imgb + ch * PLANE;
            v[ch][0] = pc[i00];
            v[ch][1] = pc[i01];
            v[ch][2] = pc[i10];
            v[ch][3] = pc[i11];
        }

#pragma unroll
        for (int ch = 0; ch < CC; ++ch) {
            float o = v[ch][0] * w00 + v[ch][1] * w01
                    + v[ch][2] * w10 + v[ch][3] * w11;
            nz |= (o != 0.f);
            __builtin_nontemporal_store(o, orow + (size_t)ch * PLANE + p * WW);
        }
    }

    // all-zero detection: one atomic per block (bn is block-uniform)
    __shared__ int s_nz;
    if (threadIdx.x == 0) s_nz = 0;
    __syncthreads();
    if (nz) s_nz = 1;            // benign race: all writers store 1
    __syncthreads();
    if (threadIdx.x == 0 && s_nz) atomicOr(&flags[bn], 1);
}

// If a (b,n) slice produced no nonzero element, overwrite it with -1.
__global__ __launch_bounds__(256) void fixup_kernel(
    float* __restrict__ out, const int* __restrict__ flags)
{
    int bn = blockIdx.x;
    if (flags[bn] != 0) return;
    float4 m1 = make_float4(-1.f, -1.f, -1.f, -1.f);
    float4* o4 = reinterpret_cast<float4*>(out + (size_t)bn * SLICE);
    for (int i = threadIdx.x; i < SLICE / 4; i += 256) o4[i] = m1;
}

extern "C" void kernel_launch(void* const* d_in, const int* in_sizes, int n_in,
                              void* d_out, int out_size, void* d_ws, size_t ws_size,
                              hipStream_t stream) {
    (void)in_sizes; (void)n_in; (void)out_size; (void)ws_size;
    const float* img = (const float*)d_in[0];
    const float* tf  = (const float*)d_in[1];
    float* out = (float*)d_out;
    int* flags = (int*)d_ws;

    hipMemsetAsync(flags, 0, BB * NN * sizeof(int), stream);

    warp_kernel<<<BB * NN * 64, 256, 0, stream>>>(img, tf, out, flags);
    fixup_kernel<<<BB * NN, 256, 0, stream>>>(out, flags);
}

// Round 4
// 52.702 us; speedup vs baseline: 2.0150x; 1.2339x over previous
//
#include <hip/hip_runtime.h>

#define BB 16
#define NN 8
#define CC 3
#define HH 256
#define WW 256
#define PLANE (HH * WW)          // 65536
#define SLICE (CC * PLANE)       // 196608 elems per (b,n)
#define BN_TOT (BB * NN)         // 128

// ws layout (packed path):
//   [0, 512):        flags[128]
//   [512, 4608):     inv[128][8] floats (ia,ib,ic,id,tx,ty,0,0)
//   [16384, +16MB):  packed [B][H][W][4] floats (c0,c1,c2,0) -> float4/pixel
#define WS_FLAGS 0
#define WS_INV   512
#define WS_PACK  16384
#define WS_NEED  (WS_PACK + (size_t)BB * PLANE * 16)

// ---------------- packed path ----------------

// 4096 blocks = 16 images * 256 rows. XCD-affine: image b on XCD b&7 so the
// packed pixels land (and stay) in that XCD's L2 for the warp kernel.
// Block 0 additionally: threads 0-127 compute inverse matrices, 128-255 zero flags.
__global__ __launch_bounds__(256) void repack_kernel(
    const float* __restrict__ img,     // [B][C][H][W]
    const float* __restrict__ tf,      // [B][N][6]
    float4* __restrict__ packed,       // [B][H][W]
    float* __restrict__ inv,           // [128][8]
    int* __restrict__ flags)
{
    int slot = blockIdx.x;
    int xcd  = slot & 7;
    int j    = slot >> 3;                 // 0..511
    int b    = xcd + ((j >> 8) << 3);     // images xcd, xcd+8
    int row  = j & 255;
    int x    = threadIdx.x;

    const float* p0 = img + (size_t)b * SLICE + (size_t)row * WW + x;
    float c0 = p0[0];
    float c1 = p0[PLANE];
    float c2 = p0[2 * PLANE];
    packed[(size_t)b * PLANE + (size_t)row * WW + x] = make_float4(c0, c1, c2, 0.f);

    if (slot == 0) {
        int t = threadIdx.x;
        if (t < BN_TOT) {
            const float* M = tf + t * 6;
            float a  = M[0], bm = M[1], tx = M[2];
            float c  = M[3], d  = M[4], ty = M[5];
            float det = a * d - bm * c;
            float* I = inv + t * 8;
            I[0] =  d / det;  I[1] = -bm / det;
            I[2] = -c / det;  I[3] =  a / det;
            I[4] = tx;        I[5] = ty;
        } else {
            flags[t - BN_TOT] = 0;
        }
    }
}

// 8192 blocks = 16 b * 8 n * 64 row-groups, XCD-affine by image.
// Thread owns one x (lane-consecutive -> coalesced gathers) and 4 rows.
// One dwordx4 gather per tap fetches all 3 channels. All 16 gathers are
// issued before any combine to maximize loads in flight.
__global__ __launch_bounds__(256) void warp_packed_kernel(
    const float4* __restrict__ packed, // [B][H][W]
    const float* __restrict__ inv,     // [128][8]
    float* __restrict__ out,           // [B][N][C][H][W]
    int* __restrict__ flags)
{
    int slot = blockIdx.x;
    int xcd  = slot & 7;
    int j    = slot >> 3;
    int b    = xcd + ((j >> 9) << 3);
    int wi   = j & 511;
    int n    = wi >> 6;
    int blk  = wi & 63;
    int bn   = (b << 3) + n;

    int x  = threadIdx.x;
    int yb = blk << 2;

    const float* I = inv + bn * 8;       // wave-uniform -> scalar loads
    float ia = I[0], ib = I[1], ic = I[2], idm = I[3];
    float tx = I[4], ty = I[5];

    const float4* pk = packed + (size_t)b * PLANE;
    float dx  = (float)x - tx;
    float sxb = ia * dx;
    float syb = ic * dx;

    // pass 1: indices + mask-folded weights for all 4 rows
    int   i00[4], i01[4], i10[4], i11[4];
    float w00[4], w01[4], w10[4], w11[4];
#pragma unroll
    for (int p = 0; p < 4; ++p) {
        float dy = (float)(yb + p) - ty;
        float sx = sxb + ib * dy;
        float sy = syb + idm * dy;
        float x0f = floorf(sx);
        float y0f = floorf(sy);
        float wx = sx - x0f;
        float wy = sy - y0f;
        int x0 = (int)x0f;
        int y0 = (int)y0f;

        float mx0 = (x0 >= 0 && x0 < WW)         ? 1.f : 0.f;
        float mx1 = (x0 + 1 >= 0 && x0 + 1 < WW) ? 1.f : 0.f;
        float my0 = (y0 >= 0 && y0 < HH)         ? 1.f : 0.f;
        float my1 = (y0 + 1 >= 0 && y0 + 1 < HH) ? 1.f : 0.f;

        int xc0 = min(max(x0, 0), WW - 1);
        int xc1 = min(max(x0 + 1, 0), WW - 1);
        int yc0 = min(max(y0, 0), HH - 1);
        int yc1 = min(max(y0 + 1, 0), HH - 1);

        i00[p] = yc0 * WW + xc0;
        i01[p] = yc0 * WW + xc1;
        i10[p] = yc1 * WW + xc0;
        i11[p] = yc1 * WW + xc1;

        w00[p] = (1.f - wx) * (1.f - wy) * (mx0 * my0);
        w01[p] = wx * (1.f - wy)         * (mx1 * my0);
        w10[p] = (1.f - wx) * wy         * (mx0 * my1);
        w11[p] = wx * wy                 * (mx1 * my1);
    }

    // pass 2: issue all 16 dwordx4 gathers
    float4 v00[4], v01[4], v10[4], v11[4];
#pragma unroll
    for (int p = 0; p < 4; ++p) {
        v00[p] = pk[i00[p]];
        v01[p] = pk[i01[p]];
        v10[p] = pk[i10[p]];
        v11[p] = pk[i11[p]];
    }

    // pass 3: combine + store (nontemporal: don't evict packed from L2)
    bool nz = false;
    float* orow = out + (size_t)bn * SLICE + (size_t)yb * WW + x;
#pragma unroll
    for (int p = 0; p < 4; ++p) {
        float o0 = v00[p].x * w00[p] + v01[p].x * w01[p]
                 + v10[p].x * w10[p] + v11[p].x * w11[p];
        float o1 = v00[p].y * w00[p] + v01[p].y * w01[p]
                 + v10[p].y * w10[p] + v11[p].y * w11[p];
        float o2 = v00[p].z * w00[p] + v01[p].z * w01[p]
                 + v10[p].z * w10[p] + v11[p].z * w11[p];
        nz |= (o0 != 0.f) | (o1 != 0.f) | (o2 != 0.f);
        __builtin_nontemporal_store(o0, orow + p * WW);
        __builtin_nontemporal_store(o1, orow + PLANE + p * WW);
        __builtin_nontemporal_store(o2, orow + 2 * PLANE + p * WW);
    }

    __shared__ int s_nz;
    if (threadIdx.x == 0) s_nz = 0;
    __syncthreads();
    if (nz) s_nz = 1;
    __syncthreads();
    if (threadIdx.x == 0 && s_nz) atomicOr(&flags[bn], 1);
}

// ---------------- fallback path (R3 kernel, known-good) ----------------

__global__ __launch_bounds__(256) void warp_kernel(
    const float* __restrict__ img,
    const float* __restrict__ tf,
    float* __restrict__ out,
    int* __restrict__ flags)
{
    int slot = blockIdx.x;
    int xcd  = slot & 7;
    int j    = slot >> 3;
    int b    = xcd + ((j >> 9) << 3);
    int wi   = j & 511;
    int n    = wi >> 6;
    int blk  = wi & 63;
    int bn   = (b << 3) + n;

    int x  = threadIdx.x;
    int yb = blk << 2;

    const float* M = tf + bn * 6;
    float a  = M[0], bm = M[1], tx = M[2];
    float c  = M[3], d  = M[4], ty = M[5];
    float det = a * d - bm * c;
    float ia  =  d / det;
    float ib  = -bm / det;
    float ic  = -c / det;
    float idm =  a / det;

    const float* imgb = img + (size_t)b * SLICE;
    float dx = (float)x - tx;
    float sxb = ia * dx;
    float syb = ic * dx;

    bool nz = false;
    float* orow = out + (size_t)bn * SLICE + (size_t)yb * WW + x;

#pragma unroll
    for (int p = 0; p < 4; ++p) {
        float dy = (float)(yb + p) - ty;
        float sx = sxb + ib * dy;
        float sy = syb + idm * dy;
        float x0f = floorf(sx);
        float y0f = floorf(sy);
        float wx = sx - x0f;
        float wy = sy - y0f;
        int x0 = (int)x0f;
        int y0 = (int)y0f;

        float mx0 = (x0 >= 0 && x0 < WW)         ? 1.f : 0.f;
        float mx1 = (x0 + 1 >= 0 && x0 + 1 < WW) ? 1.f : 0.f;
        float my0 = (y0 >= 0 && y0 < HH)         ? 1.f : 0.f;
        float my1 = (y0 + 1 >= 0 && y0 + 1 < HH) ? 1.f : 0.f;

        int xc0 = min(max(x0, 0), WW - 1);
        int xc1 = min(max(x0 + 1, 0), WW - 1);
        int yc0 = min(max(y0, 0), HH - 1);
        int yc1 = min(max(y0 + 1, 0), HH - 1);

        int i00 = yc0 * WW + xc0;
        int i01 = yc0 * WW + xc1;
        int i10 = yc1 * WW + xc0;
        int i11 = yc1 * WW + xc1;

        float w00 = (1.f - wx) * (1.f - wy) * (mx0 * my0);
        float w01 = wx * (1.f - wy)         * (mx1 * my0);
        float w10 = (1.f - wx) * wy         * (mx0 * my1);
        float w11 = wx * wy                 * (mx1 * my1);

        float v[CC][4];
#pragma unroll
        for (int ch = 0; ch < CC; ++ch) {
            const float* pc = imgb + ch * PLANE;
            v[ch][0] = pc[i00];
            v[ch][1] = pc[i01];
            v[ch][2] = pc[i10];
            v[ch][3] = pc[i11];
        }

#pragma unroll
        for (int ch = 0; ch < CC; ++ch) {
            float o = v[ch][0] * w00 + v[ch][1] * w01
                    + v[ch][2] * w10 + v[ch][3] * w11;
            nz |= (o != 0.f);
            __builtin_nontemporal_store(o, orow + (size_t)ch * PLANE + p * WW);
        }
    }

    __shared__ int s_nz;
    if (threadIdx.x == 0) s_nz = 0;
    __syncthreads();
    if (nz) s_nz = 1;
    __syncthreads();
    if (threadIdx.x == 0 && s_nz) atomicOr(&flags[bn], 1);
}

__global__ __launch_bounds__(256) void fixup_kernel(
    float* __restrict__ out, const int* __restrict__ flags)
{
    int bn = blockIdx.x;
    if (flags[bn] != 0) return;
    float4 m1 = make_float4(-1.f, -1.f, -1.f, -1.f);
    float4* o4 = reinterpret_cast<float4*>(out + (size_t)bn * SLICE);
    for (int i = threadIdx.x; i < SLICE / 4; i += 256) o4[i] = m1;
}

extern "C" void kernel_launch(void* const* d_in, const int* in_sizes, int n_in,
                              void* d_out, int out_size, void* d_ws, size_t ws_size,
                              hipStream_t stream) {
    (void)in_sizes; (void)n_in; (void)out_size;
    const float* img = (const float*)d_in[0];
    const float* tf  = (const float*)d_in[1];
    float* out = (float*)d_out;
    char* ws = (char*)d_ws;
    int* flags = (int*)(ws + WS_FLAGS);

    if (ws_size >= WS_NEED) {
        float4* packed = (float4*)(ws + WS_PACK);
        float*  inv    = (float*)(ws + WS_INV);
        repack_kernel<<<BB * HH, 256, 0, stream>>>(img, tf, packed, inv, flags);
        warp_packed_kernel<<<BB * NN * 64, 256, 0, stream>>>(packed, inv, out, flags);
    } else {
        hipMemsetAsync(flags, 0, BN_TOT * sizeof(int), stream);
        warp_kernel<<<BB * NN * 64, 256, 0, stream>>>(img, tf, out, flags);
    }
    fixup_kernel<<<BN_TOT, 256, 0, stream>>>(out, flags);
}

// Round 5
// 49.367 us; speedup vs baseline: 2.1511x; 1.0675x over previous
//
#include <hip/hip_runtime.h>

#define BB 16
#define NN 8
#define CC 3
#define HH 256
#define WW 256
#define PLANE (HH * WW)          // 65536
#define SLICE (CC * PLANE)       // 196608 elems per (b,n)
#define BN_TOT (BB * NN)         // 128

// ws layout (packed path):
//   [0, 512):       flags[128]
//   [512, 4608):    inv[128][8] floats (ia,ib,ic,id,tx,ty,0,0)
//   [16384, +8MB):  packed [B][H][W] of 2 dwords/pixel: d0=bf16(c0)|bf16(c1)<<16, d1=bf16(c2)
#define WS_FLAGS 0
#define WS_INV   512
#define WS_PACK  16384
#define WS_NEED  (WS_PACK + (size_t)BB * PLANE * 8 + 64)

typedef unsigned int u32;
typedef u32 __attribute__((ext_vector_type(4))) u32x4;
typedef u32x4 __attribute__((aligned(8))) u32x4_a8;   // 8B-aligned 16B load

__device__ __forceinline__ u32 f2bf(float f) {        // RNE f32 -> bf16
    u32 u = __float_as_uint(f);
    return (u + 0x7fffu + ((u >> 16) & 1u)) >> 16;
}
__device__ __forceinline__ float bflo(u32 d) { return __uint_as_float(d << 16); }
__device__ __forceinline__ float bfhi(u32 d) { return __uint_as_float(d & 0xffff0000u); }

// ---------------- packed path ----------------

// 4096 blocks = 16 images * 256 rows, XCD-affine (image b on XCD b&7).
// Block 0 also computes inverse matrices (threads 0-127) and zeroes flags (128-255).
__global__ __launch_bounds__(256) void repack_kernel(
    const float* __restrict__ img,     // [B][C][H][W]
    const float* __restrict__ tf,      // [B][N][6]
    uint2* __restrict__ packed,        // [B][H][W]
    float* __restrict__ inv,           // [128][8]
    int* __restrict__ flags)
{
    int slot = blockIdx.x;
    int xcd  = slot & 7;
    int j    = slot >> 3;                 // 0..511
    int b    = xcd + ((j >> 8) << 3);     // images xcd, xcd+8
    int row  = j & 255;
    int x    = threadIdx.x;

    const float* p0 = img + (size_t)b * SLICE + (size_t)row * WW + x;
    u32 h0 = f2bf(p0[0]);
    u32 h1 = f2bf(p0[PLANE]);
    u32 h2 = f2bf(p0[2 * PLANE]);
    uint2 d;
    d.x = h0 | (h1 << 16);
    d.y = h2;
    packed[(size_t)b * PLANE + (size_t)row * WW + x] = d;

    if (slot == 0) {
        int t = threadIdx.x;
        if (t < BN_TOT) {
            const float* M = tf + t * 6;
            float a  = M[0], bm = M[1], tx = M[2];
            float c  = M[3], dd = M[4], ty = M[5];
            float det = a * dd - bm * c;
            float* I = inv + t * 8;
            I[0] =  dd / det;  I[1] = -bm / det;
            I[2] = -c / det;   I[3] =  a / det;
            I[4] = tx;         I[5] = ty;
        } else {
            flags[t - BN_TOT] = 0;
        }
    }
}

// 8192 blocks = 16 b * 8 n * 64 row-groups, XCD-affine by image.
// Thread owns one x (lane-consecutive -> coalesced gathers) and 4 rows.
// ONE 16B gather per y-tap fetches BOTH x-taps (pixels xc0, xc0+1) x 3 ch
// in bf16 -> 8 gathers/thread. All 8 issued before any combine.
__global__ __launch_bounds__(256) void warp_packed_kernel(
    const u32* __restrict__ pk,        // [B][PLANE][2] dwords
    const float* __restrict__ inv,     // [128][8]
    float* __restrict__ out,           // [B][N][C][H][W]
    int* __restrict__ flags)
{
    int slot = blockIdx.x;
    int xcd  = slot & 7;
    int j    = slot >> 3;
    int b    = xcd + ((j >> 9) << 3);
    int wi   = j & 511;
    int n    = wi >> 6;
    int blk  = wi & 63;
    int bn   = (b << 3) + n;

    int x  = threadIdx.x;
    int yb = blk << 2;

    const float* I = inv + bn * 8;       // wave-uniform -> scalar loads
    float ia = I[0], ib = I[1], ic = I[2], idm = I[3];
    float tx = I[4], ty = I[5];

    const u32* pb = pk + (size_t)b * (PLANE * 2);
    float dx  = (float)x - tx;
    float sxb = ia * dx;
    float syb = ic * dx;

    // pass 1: pair offsets + x-select + mask-folded weights, all 4 rows
    int   ofT[4], ofB[4];
    bool  xin[4];
    float w00[4], w01[4], w10[4], w11[4];
#pragma unroll
    for (int p = 0; p < 4; ++p) {
        float dy = (float)(yb + p) - ty;
        float sx = sxb + ib * dy;
        float sy = syb + idm * dy;
        float x0f = floorf(sx);
        float y0f = floorf(sy);
        float wx = sx - x0f;
        float wy = sy - y0f;
        int x0 = (int)x0f;
        int y0 = (int)y0f;

        float mx0 = (x0 >= 0 && x0 < WW)         ? 1.f : 0.f;
        float mx1 = (x0 + 1 >= 0 && x0 + 1 < WW) ? 1.f : 0.f;
        float my0 = (y0 >= 0 && y0 < HH)         ? 1.f : 0.f;
        float my1 = (y0 + 1 >= 0 && y0 + 1 < HH) ? 1.f : 0.f;

        int xc0 = min(max(x0, 0), WW - 1);
        int yc0 = min(max(y0, 0), HH - 1);
        int yc1 = min(max(y0 + 1, 0), HH - 1);

        xin[p] = (x0 >= 0);                  // else x1-tap value = lo pixel
        ofT[p] = (yc0 * WW + xc0) * 2;
        ofB[p] = (yc1 * WW + xc0) * 2;

        w00[p] = (1.f - wx) * (1.f - wy) * (mx0 * my0);
        w01[p] = wx * (1.f - wy)         * (mx1 * my0);
        w10[p] = (1.f - wx) * wy         * (mx0 * my1);
        w11[p] = wx * wy                 * (mx1 * my1);
    }

    // pass 2: issue all 8 pair-gathers (16B each, 8B-aligned)
    u32x4 vt[4], vb[4];
#pragma unroll
    for (int p = 0; p < 4; ++p) {
        vt[p] = *reinterpret_cast<const u32x4_a8*>(pb + ofT[p]);
        vb[p] = *reinterpret_cast<const u32x4_a8*>(pb + ofB[p]);
    }

    // pass 3: select x-tap, decode bf16, combine, store
    bool nz = false;
    float* orow = out + (size_t)bn * SLICE + (size_t)yb * WW + x;
#pragma unroll
    for (int p = 0; p < 4; ++p) {
        u32 a0 = vt[p].x, a1 = vt[p].y;                       // v00
        u32 b0 = xin[p] ? vt[p].z : vt[p].x;                  // v01
        u32 b1 = xin[p] ? vt[p].w : vt[p].y;
        u32 c0 = vb[p].x, c1 = vb[p].y;                       // v10
        u32 d0 = xin[p] ? vb[p].z : vb[p].x;                  // v11
        u32 d1 = xin[p] ? vb[p].w : vb[p].y;

        float o0 = bflo(a0) * w00[p] + bflo(b0) * w01[p]
                 + bflo(c0) * w10[p] + bflo(d0) * w11[p];
        float o1 = bfhi(a0) * w00[p] + bfhi(b0) * w01[p]
                 + bfhi(c0) * w10[p] + bfhi(d0) * w11[p];
        float o2 = bflo(a1) * w00[p] + bflo(b1) * w01[p]
                 + bflo(c1) * w10[p] + bflo(d1) * w11[p];
        nz |= (o0 != 0.f) | (o1 != 0.f) | (o2 != 0.f);
        __builtin_nontemporal_store(o0, orow + p * WW);
        __builtin_nontemporal_store(o1, orow + PLANE + p * WW);
        __builtin_nontemporal_store(o2, orow + 2 * PLANE + p * WW);
    }

    __shared__ int s_nz;
    if (threadIdx.x == 0) s_nz = 0;
    __syncthreads();
    if (nz) s_nz = 1;
    __syncthreads();
    if (threadIdx.x == 0 && s_nz) atomicOr(&flags[bn], 1);
}

// ---------------- fallback path (R3 kernel, known-good, f32 direct) ----------------

__global__ __launch_bounds__(256) void warp_kernel(
    const float* __restrict__ img,
    const float* __restrict__ tf,
    float* __restrict__ out,
    int* __restrict__ flags)
{
    int slot = blockIdx.x;
    int xcd  = slot & 7;
    int j    = slot >> 3;
    int b    = xcd + ((j >> 9) << 3);
    int wi   = j & 511;
    int n    = wi >> 6;
    int blk  = wi & 63;
    int bn   = (b << 3) + n;

    int x  = threadIdx.x;
    int yb = blk << 2;

    const float* M = tf + bn * 6;
    float a  = M[0], bm = M[1], tx = M[2];
    float c  = M[3], d  = M[4], ty = M[5];
    float det = a * d - bm * c;
    float ia  =  d / det;
    float ib  = -bm / det;
    float ic  = -c / det;
    float idm =  a / det;

    const float* imgb = img + (size_t)b * SLICE;
    float dx = (float)x - tx;
    float sxb = ia * dx;
    float syb = ic * dx;

    bool nz = false;
    float* orow = out + (size_t)bn * SLICE + (size_t)yb * WW + x;

#pragma unroll
    for (int p = 0; p < 4; ++p) {
        float dy = (float)(yb + p) - ty;
        float sx = sxb + ib * dy;
        float sy = syb + idm * dy;
        float x0f = floorf(sx);
        float y0f = floorf(sy);
        float wx = sx - x0f;
        float wy = sy - y0f;
        int x0 = (int)x0f;
        int y0 = (int)y0f;

        float mx0 = (x0 >= 0 && x0 < WW)         ? 1.f : 0.f;
        float mx1 = (x0 + 1 >= 0 && x0 + 1 < WW) ? 1.f : 0.f;
        float my0 = (y0 >= 0 && y0 < HH)         ? 1.f : 0.f;
        float my1 = (y0 + 1 >= 0 && y0 + 1 < HH) ? 1.f : 0.f;

        int xc0 = min(max(x0, 0), WW - 1);
        int xc1 = min(max(x0 + 1, 0), WW - 1);
        int yc0 = min(max(y0, 0), HH - 1);
        int yc1 = min(max(y0 + 1, 0), HH - 1);

        int i00 = yc0 * WW + xc0;
        int i01 = yc0 * WW + xc1;
        int i10 = yc1 * WW + xc0;
        int i11 = yc1 * WW + xc1;

        float w00 = (1.f - wx) * (1.f - wy) * (mx0 * my0);
        float w01 = wx * (1.f - wy)         * (mx1 * my0);
        float w10 = (1.f - wx) * wy         * (mx0 * my1);
        float w11 = wx * wy                 * (mx1 * my1);

        float v[CC][4];
#pragma unroll
        for (int ch = 0; ch < CC; ++ch) {
            const float* pc = imgb + ch * PLANE;
            v[ch][0] = pc[i00];
            v[ch][1] = pc[i01];
            v[ch][2] = pc[i10];
            v[ch][3] = pc[i11];
        }

#pragma unroll
        for (int ch = 0; ch < CC; ++ch) {
            float o = v[ch][0] * w00 + v[ch][1] * w01
                    + v[ch][2] * w10 + v[ch][3] * w11;
            nz |= (o != 0.f);
            __builtin_nontemporal_store(o, orow + (size_t)ch * PLANE + p * WW);
        }
    }

    __shared__ int s_nz;
    if (threadIdx.x == 0) s_nz = 0;
    __syncthreads();
    if (nz) s_nz = 1;
    __syncthreads();
    if (threadIdx.x == 0 && s_nz) atomicOr(&flags[bn], 1);
}

__global__ __launch_bounds__(256) void fixup_kernel(
    float* __restrict__ out, const int* __restrict__ flags)
{
    int bn = blockIdx.x;
    if (flags[bn] != 0) return;
    float4 m1 = make_float4(-1.f, -1.f, -1.f, -1.f);
    float4* o4 = reinterpret_cast<float4*>(out + (size_t)bn * SLICE);
    for (int i = threadIdx.x; i < SLICE / 4; i += 256) o4[i] = m1;
}

extern "C" void kernel_launch(void* const* d_in, const int* in_sizes, int n_in,
                              void* d_out, int out_size, void* d_ws, size_t ws_size,
                              hipStream_t stream) {
    (void)in_sizes; (void)n_in; (void)out_size;
    const float* img = (const float*)d_in[0];
    const float* tf  = (const float*)d_in[1];
    float* out = (float*)d_out;
    char* ws = (char*)d_ws;
    int* flags = (int*)(ws + WS_FLAGS);

    if (ws_size >= WS_NEED) {
        uint2* packed = (uint2*)(ws + WS_PACK);
        float* inv    = (float*)(ws + WS_INV);
        repack_kernel<<<BB * HH, 256, 0, stream>>>(img, tf, packed, inv, flags);
        warp_packed_kernel<<<BB * NN * 64, 256, 0, stream>>>((const u32*)packed, inv, out, flags);
    } else {
        hipMemsetAsync(flags, 0, BN_TOT * sizeof(int), stream);
        warp_kernel<<<BB * NN * 64, 256, 0, stream>>>(img, tf, out, flags);
    }
    fixup_kernel<<<BN_TOT, 256, 0, stream>>>(out, flags);
}